// Round 5
// baseline (154.866 us; speedup 1.0000x reference)
//
#include <hip/hip_runtime.h>
#include <hip/hip_bf16.h>
#include <cstdint>

#define B_ 8
#define C_ 128
#define N_ 16384  // H*W
#define CHN 256   // n per KA block
#define SN 64     // n per KA subtile
#define NST 4     // subtiles per block
#define NC (N_ / CHN)  // 64 chunks

typedef __attribute__((ext_vector_type(8))) short short8;
typedef __attribute__((ext_vector_type(4))) float f32x4;
typedef __attribute__((ext_vector_type(4))) unsigned short us4;
typedef unsigned short u16;

__device__ __forceinline__ short f2bf(float f) {
  union { float f; unsigned u; } c; c.f = f;
  unsigned r = (c.u + 0x7FFFu + ((c.u >> 16) & 1u)) >> 16;
  return (short)r;
}

__device__ __forceinline__ unsigned cvtpk(float lo, float hi) {
  unsigned r;
  asm("v_cvt_pk_bf16_f32 %0, %1, %2" : "=v"(r) : "v"(lo), "v"(hi));
  return r;
}

union SB { short8 s8; unsigned u[4]; };

__device__ __forceinline__ void gl_lds16(const float* g, float* l) {
  __builtin_amdgcn_global_load_lds(
      (const __attribute__((address_space(1))) void*)g,
      (__attribute__((address_space(3))) void*)l, 16, 0, 0);
}

// slot swizzle for fp32 [row][64] tiles
__device__ __forceinline__ int swz(int row) { return (row ^ (row >> 2)) & 7; }

// ---------------------------------------------------------------------------
// K0: preconvert k_w, v_w (fp32) -> wbf (bf16 [2][128][128])
// ---------------------------------------------------------------------------
__global__ __launch_bounds__(256) void k0_wcvt(const float* __restrict__ kw,
                                               const float* __restrict__ vw,
                                               u16* __restrict__ wbf) {
  const int g = blockIdx.x * 256 + threadIdx.x;  // 0..8191 float4s
  const int mat = g >> 12, o4 = g & 4095;
  const float* src = mat ? vw : kw;
  float4 f = reinterpret_cast<const float4*>(src)[o4];
  us4 s;
  s[0] = (u16)f2bf(f.x); s[1] = (u16)f2bf(f.y);
  s[2] = (u16)f2bf(f.z); s[3] = (u16)f2bf(f.w);
  reinterpret_cast<us4*>(wbf + (size_t)mat * C_ * C_)[o4] = s;
}

// ---------------------------------------------------------------------------
// KA: fused projection + context partial (V-path, round-3 algebra).
//   EK[d,n] = exp(kw·x + kb);  V[c,n] = vw·x + vb (both bf16 LDS stash)
//   part[kc][b][c][d] = sum_n V·EK;  zpart[kc][b][d] = sum_n EK
// grid (NC, B), 512 thr = 8 waves, 64KB LDS -> 2 blocks/CU.
// proj role: mat = w>>2 (0:EK 1:V), dblk = w&3 -> 32 d-rows, all 64 n.
//   Swapped MFMA (A = x-frag rows n, B = W rows d) -> D[n][d].
// ctx role: cg = w>>1 (32 c), dh = w&1 (64 d).
// Pipelining: ctx reads only stashes, so next x-subtile staging is issued
// right after the post-stash barrier and flies under the ctx MFMAs.
// ---------------------------------------------------------------------------
__global__ __launch_bounds__(512, 4) void ka_projctx(
    const float* __restrict__ kv, const u16* __restrict__ wbf,
    const float* __restrict__ kb, const float* __restrict__ vb,
    float* __restrict__ part, float* __restrict__ zpart) {
  __shared__ char lds[65536];
  float* xs = (float*)lds;            // [128][64] fp32 swizzled (32 KB)
  u16*  eks = (u16*)(lds + 32768);    // [128][64] bf16 swizzled (16 KB)
  u16*  vs  = (u16*)(lds + 49152);    // [128][64] bf16 swizzled (16 KB)

  const int b = blockIdx.y, kc = blockIdx.x;
  const int tid = threadIdx.x;
  const int w = tid >> 6, lane = tid & 63;
  const int lg = lane >> 4, li = lane & 15;
  const int mat = w >> 2, dblk = w & 3;
  const int cg = w >> 1, dh = w & 1;
  const int r_in = lane >> 4, slot = lane & 15;

  const float* xb = kv + (size_t)b * C_ * N_ + kc * CHN;
  const u16* W = wbf + (size_t)mat * C_ * C_;
  const float* biasp = mat ? vb : kb;

  // W fragments (B-operand rows d) + biases, registers (L2-hot)
  short8 wreg[2][4];
#pragma unroll
  for (int dt = 0; dt < 2; ++dt)
#pragma unroll
    for (int ks = 0; ks < 4; ++ks)
      wreg[dt][ks] = *reinterpret_cast<const short8*>(
          W + (dblk * 32 + dt * 16 + li) * C_ + ks * 32 + lg * 8);
  float bias2[2];
#pragma unroll
  for (int dt = 0; dt < 2; ++dt) bias2[dt] = biasp[dblk * 32 + dt * 16 + li];

  f32x4 acc[2][4] = {};  // ctx accumulator [am c][dt d]
  float zac[2] = {0.f, 0.f};

  // prologue: stage subtile 0 (4 rows x 256B per instr, pre-swizzled source)
#pragma unroll
  for (int i = 0; i < 4; ++i) {
    const int row = w * 16 + i * 4 + r_in;
    gl_lds16(xb + (size_t)row * N_ + 4 * (slot ^ swz(row)), xs + (w * 16 + i * 4) * SN);
  }

  for (int st = 0; st < NST; ++st) {
    asm volatile("s_waitcnt vmcnt(0) lgkmcnt(0)" ::: "memory");
    __builtin_amdgcn_s_barrier();
    __builtin_amdgcn_sched_barrier(0);

    // ---- proj + stash, in nt-pairs (keeps pacc at 16 VGPRs) ----
    u16* S = mat ? vs : eks;
#pragma unroll
    for (int h = 0; h < 2; ++h) {
      f32x4 pacc[2][2] = {};  // [ntl][dt]
#pragma unroll
      for (int ntl = 0; ntl < 2; ++ntl) {
        const int n = (h * 2 + ntl) * 16 + li;
#pragma unroll
        for (int ks = 0; ks < 4; ++ks) {
          SB sb;
#pragma unroll
          for (int p = 0; p < 4; ++p) {
            const int c0 = ks * 32 + lg * 8 + 2 * p;
            const float f0 = xs[c0 * SN + (n ^ (swz(c0) << 2))];
            const float f1 = xs[(c0 + 1) * SN + (n ^ (swz(c0 + 1) << 2))];
            sb.u[p] = cvtpk(f0, f1);
          }
#pragma unroll
          for (int dt = 0; dt < 2; ++dt)
            pacc[ntl][dt] = __builtin_amdgcn_mfma_f32_16x16x32_bf16(
                sb.s8, wreg[dt][ks], pacc[ntl][dt], 0, 0, 0);
        }
      }
#pragma unroll
      for (int dt = 0; dt < 2; ++dt) {
        const int d = dblk * 32 + dt * 16 + li;
        const float bias = bias2[dt];
#pragma unroll
        for (int ntl = 0; ntl < 2; ++ntl) {
          float v0 = pacc[ntl][dt][0] + bias;
          float v1 = pacc[ntl][dt][1] + bias;
          float v2 = pacc[ntl][dt][2] + bias;
          float v3 = pacc[ntl][dt][3] + bias;
          if (mat == 0) {
            v0 = __expf(v0); v1 = __expf(v1); v2 = __expf(v2); v3 = __expf(v3);
            zac[dt] += (v0 + v1) + (v2 + v3);
          }
          const int nq = (h * 2 + ntl) * 16 + lg * 4;
          uint2 pk; pk.x = cvtpk(v0, v1); pk.y = cvtpk(v2, v3);
          *reinterpret_cast<uint2*>(S + d * SN + (nq ^ ((d & 7) << 3))) = pk;
        }
      }
    }
    asm volatile("s_waitcnt lgkmcnt(0)" ::: "memory");
    __builtin_amdgcn_s_barrier();
    __builtin_amdgcn_sched_barrier(0);

    // ---- issue next-subtile staging (xs free; flies under ctx MFMAs) ----
    if (st < NST - 1) {
      const float* xbs = xb + (size_t)(st + 1) * SN;
#pragma unroll
      for (int i = 0; i < 4; ++i) {
        const int row = w * 16 + i * 4 + r_in;
        gl_lds16(xbs + (size_t)row * N_ + 4 * (slot ^ swz(row)), xs + (w * 16 + i * 4) * SN);
      }
    }

    // ---- ctx: part += V·EK^T over this subtile's 64 n ----
#pragma unroll
    for (int kk = 0; kk < 2; ++kk) {
      const int n0 = kk * 32 + lg * 8;
      short8 a[2], bb[4];
#pragma unroll
      for (int am = 0; am < 2; ++am) {
        const int c = cg * 32 + am * 16 + li;
        a[am] = *reinterpret_cast<const short8*>(vs + c * SN + (n0 ^ ((c & 7) << 3)));
      }
#pragma unroll
      for (int dt = 0; dt < 4; ++dt) {
        const int d = dh * 64 + dt * 16 + li;
        bb[dt] = *reinterpret_cast<const short8*>(eks + d * SN + (n0 ^ ((d & 7) << 3)));
      }
#pragma unroll
      for (int am = 0; am < 2; ++am)
#pragma unroll
        for (int dt = 0; dt < 4; ++dt)
          acc[am][dt] = __builtin_amdgcn_mfma_f32_16x16x32_bf16(a[am], bb[dt], acc[am][dt], 0, 0, 0);
    }
  }

  // ---- epilogue: part + zpart (deterministic, no atomics) ----
  float* P = part + ((size_t)kc * B_ + b) * C_ * C_;
#pragma unroll
  for (int am = 0; am < 2; ++am)
#pragma unroll
    for (int dt = 0; dt < 4; ++dt)
#pragma unroll
      for (int r = 0; r < 4; ++r) {
        const int c = cg * 32 + am * 16 + lg * 4 + r;
        const int d = dh * 64 + dt * 16 + li;
        P[c * C_ + d] = acc[am][dt][r];
      }
  if (mat == 0) {
#pragma unroll
    for (int dt = 0; dt < 2; ++dt) {
      float z = zac[dt];
      z += __shfl_xor(z, 16);
      z += __shfl_xor(z, 32);
      if (lg == 0)
        zpart[((size_t)kc * B_ + b) * C_ + dblk * 32 + dt * 16 + li] = z;
    }
  }
}

// ---------------------------------------------------------------------------
// KB1: Psum[b] = sum_kc part[kc][b]   grid (32, B), 128 thr
// ---------------------------------------------------------------------------
__global__ __launch_bounds__(128) void kb1_red(const float* __restrict__ part,
                                               float* __restrict__ Psum) {
  const int g = blockIdx.x, b = blockIdx.y, t = threadIdx.x;
  const float4* P4 = reinterpret_cast<const float4*>(part);
  float ax = 0.f, ay = 0.f, az = 0.f, aw = 0.f;
#pragma unroll 4
  for (int kc = 0; kc < NC; ++kc) {
    float4 v = P4[((size_t)kc * B_ + b) * 4096 + g * 128 + t];
    ax += v.x; ay += v.y; az += v.z; aw += v.w;
  }
  float4 o; o.x = ax; o.y = ay; o.z = az; o.w = aw;
  reinterpret_cast<float4*>(Psum)[(size_t)b * 4096 + g * 128 + t] = o;
}

// ---------------------------------------------------------------------------
// KB2: cs = Psum/Z ; M = cs·qw (bf16), T = cs·qb
// grid (8, B), 256 thr; block owns 16 c-rows.
// ---------------------------------------------------------------------------
__global__ __launch_bounds__(256) void kb2_fin(
    const float* __restrict__ Psum, const float* __restrict__ zpart,
    const float* __restrict__ qw, const float* __restrict__ qb,
    u16* __restrict__ M, float* __restrict__ T) {
  const int b = blockIdx.y;
  const int cs0 = blockIdx.x * 16;
  const int tid = threadIdx.x;
  __shared__ float cs[16][128];
  __shared__ float Zs[128];
  if (tid < 128) {
    float s = 0.f;
    for (int kc = 0; kc < NC; ++kc)
      s += zpart[((size_t)kc * B_ + b) * C_ + tid];
    Zs[tid] = s;
  }
  __syncthreads();
#pragma unroll
  for (int i = 0; i < 8; ++i) {
    const int e = tid + i * 256;
    const int cl = e >> 7, d = e & 127;
    cs[cl][d] = Psum[((size_t)b * C_ + cs0 + cl) * C_ + d] / Zs[d];
  }
  __syncthreads();
  const int cl = tid >> 4, e0 = (tid & 15) * 8;
  float m[8] = {};
  for (int d = 0; d < 128; ++d) {
    const float cv = cs[cl][d];
    const float* qr = qw + d * C_ + e0;
#pragma unroll
    for (int j = 0; j < 8; ++j) m[j] += cv * qr[j];
  }
  u16* mp = M + ((size_t)b * C_ + cs0 + cl) * C_ + e0;
#pragma unroll
  for (int j = 0; j < 8; ++j) mp[j] = (u16)f2bf(m[j]);
  if (tid < 16) {
    float tv = 0.f;
    for (int d = 0; d < 128; ++d) tv += cs[tid][d] * qb[d];
    T[b * C_ + cs0 + tid] = tv;
  }
}

// ---------------------------------------------------------------------------
// K4: out = M·q_feat + T (fp32).  grid (N/64, B), 256 thr = 4 waves.
// Swapped-operand MFMA -> D[n][c]: float4 stores.  M in registers.
// ---------------------------------------------------------------------------
__global__ __launch_bounds__(256) void k4_out(const u16* __restrict__ M,
                                              const float* __restrict__ T,
                                              const float* __restrict__ q,
                                              float* __restrict__ out) {
  __shared__ float qs[C_ * SN];  // [d][64] fp32 swizzled, 32 KB
  const int b = blockIdx.y;
  const int n0 = blockIdx.x * 64;
  const int tid = threadIdx.x;
  const int w = tid >> 6, lane = tid & 63;
  const int lg = lane >> 4, li = lane & 15;
  const int r_in = lane >> 4, slot = lane & 15;

  const float* qbp = q + (size_t)b * C_ * N_ + n0;
#pragma unroll
  for (int i = 0; i < 8; ++i) {
    const int row = w * 32 + i * 4 + r_in;
    gl_lds16(qbp + (size_t)row * N_ + 4 * (slot ^ swz(row)), qs + (w * 32 + i * 4) * SN);
  }

  short8 mreg[2][4];
  const u16* Mb = M + (size_t)b * C_ * C_;
#pragma unroll
  for (int ct = 0; ct < 2; ++ct)
#pragma unroll
    for (int ks = 0; ks < 4; ++ks)
      mreg[ct][ks] = *reinterpret_cast<const short8*>(
          Mb + (w * 32 + ct * 16 + li) * C_ + ks * 32 + lg * 8);
  float tc[2];
#pragma unroll
  for (int ct = 0; ct < 2; ++ct) tc[ct] = T[b * C_ + w * 32 + ct * 16 + li];

  __syncthreads();

  f32x4 acc[2][4] = {};  // [ct][nt]
#pragma unroll
  for (int nt = 0; nt < 4; ++nt) {
    const int n = nt * 16 + li;
#pragma unroll
    for (int ks = 0; ks < 4; ++ks) {
      SB sb;
#pragma unroll
      for (int p = 0; p < 4; ++p) {
        const int d0 = ks * 32 + lg * 8 + 2 * p;
        const float f0 = qs[d0 * SN + (n ^ (swz(d0) << 2))];
        const float f1 = qs[(d0 + 1) * SN + (n ^ (swz(d0 + 1) << 2))];
        sb.u[p] = cvtpk(f0, f1);
      }
#pragma unroll
      for (int ct = 0; ct < 2; ++ct)
        acc[ct][nt] = __builtin_amdgcn_mfma_f32_16x16x32_bf16(sb.s8, mreg[ct][ks], acc[ct][nt], 0, 0, 0);
    }
  }

#pragma unroll
  for (int ct = 0; ct < 2; ++ct) {
    const int c = w * 32 + ct * 16 + li;
    float* op = out + ((size_t)b * C_ + c) * N_ + n0;
#pragma unroll
    for (int nt = 0; nt < 4; ++nt) {
      float4 v;
      v.x = acc[ct][nt][0] + tc[ct];
      v.y = acc[ct][nt][1] + tc[ct];
      v.z = acc[ct][nt][2] + tc[ct];
      v.w = acc[ct][nt][3] + tc[ct];
      *reinterpret_cast<float4*>(op + nt * 16 + lg * 4) = v;
    }
  }
}

// ---------------------------------------------------------------------------
extern "C" void kernel_launch(void* const* d_in, const int* in_sizes, int n_in,
                              void* d_out, int out_size, void* d_ws, size_t ws_size,
                              hipStream_t stream) {
  const float* q_feat  = (const float*)d_in[0];
  const float* kv_feat = (const float*)d_in[1];
  const float* q_w = (const float*)d_in[2];
  const float* q_b = (const float*)d_in[3];
  const float* k_w = (const float*)d_in[4];
  const float* k_b = (const float*)d_in[5];
  const float* v_w = (const float*)d_in[6];
  const float* v_b = (const float*)d_in[7];
  float* out = (float*)d_out;

  char* ws = (char*)d_ws;
  const size_t szPart = (size_t)NC * B_ * C_ * C_ * sizeof(float);  // 32 MB
  const size_t szZp   = (size_t)NC * B_ * C_ * sizeof(float);       // 256 KB
  const size_t szPs   = (size_t)B_ * C_ * C_ * sizeof(float);       // 512 KB
  const size_t szWbf  = (size_t)2 * C_ * C_ * sizeof(u16);          // 64 KB
  const size_t szM    = (size_t)B_ * C_ * C_ * sizeof(u16);         // 256 KB

  float* part  = (float*)ws;
  float* zpart = (float*)(ws + szPart);
  float* Psum  = (float*)(ws + szPart + szZp);
  u16*   wbf   = (u16*)(ws + szPart + szZp + szPs);
  u16*   M     = (u16*)(ws + szPart + szZp + szPs + szWbf);
  float* T     = (float*)(ws + szPart + szZp + szPs + szWbf + szM);

  k0_wcvt<<<dim3(32), 256, 0, stream>>>(k_w, v_w, wbf);
  ka_projctx<<<dim3(NC, B_), 512, 0, stream>>>(kv_feat, wbf, k_b, v_b, part, zpart);
  kb1_red<<<dim3(32, B_), 128, 0, stream>>>(part, Psum);
  kb2_fin<<<dim3(8, B_), 256, 0, stream>>>(Psum, zpart, q_w, q_b, M, T);
  k4_out<<<dim3(N_ / 64, B_), 256, 0, stream>>>(M, T, q_feat, out);
}

// Round 6
// 78.890 us; speedup vs baseline: 1.9631x; 1.9631x over previous
//
#include <hip/hip_runtime.h>
#include <hip/hip_bf16.h>
#include <cstdint>

#define B_ 8
#define C_ 128
#define N_ 16384   // H*W
#define CHN 512    // n per KA block
#define SN 128     // n per KA subtile
#define NST 4      // subtiles per KA block
#define NC (N_ / CHN)  // 32 chunks
#define SN4 64     // n per K4 block

typedef __attribute__((ext_vector_type(8))) short short8;
typedef __attribute__((ext_vector_type(4))) float f32x4;
typedef __attribute__((ext_vector_type(4))) unsigned short us4;
typedef unsigned short u16;

__device__ __forceinline__ short f2bf(float f) {
  union { float f; unsigned u; } c; c.f = f;
  unsigned r = (c.u + 0x7FFFu + ((c.u >> 16) & 1u)) >> 16;
  return (short)r;
}

__device__ __forceinline__ unsigned cvtpk(float lo, float hi) {
  unsigned r;
  asm("v_cvt_pk_bf16_f32 %0, %1, %2" : "=v"(r) : "v"(lo), "v"(hi));
  return r;
}

union SB { short8 s8; unsigned u[4]; };

__device__ __forceinline__ void gl_lds16(const float* g, float* l) {
  __builtin_amdgcn_global_load_lds(
      (const __attribute__((address_space(1))) void*)g,
      (__attribute__((address_space(3))) void*)l, 16, 0, 0);
}

// slot swizzle for fp32 [row][64] tiles (K4 staging)
__device__ __forceinline__ int swz(int row) { return (row ^ (row >> 2)) & 7; }

// ---------------------------------------------------------------------------
// K0: preconvert k_w, v_w (fp32) -> wbf (bf16 [2][128][128])
// ---------------------------------------------------------------------------
__global__ __launch_bounds__(256) void k0_wcvt(const float* __restrict__ kw,
                                               const float* __restrict__ vw,
                                               u16* __restrict__ wbf) {
  const int g = blockIdx.x * 256 + threadIdx.x;  // 0..8191 float4s
  const int mat = g >> 12, o4 = g & 4095;
  const float* src = mat ? vw : kw;
  float4 f = reinterpret_cast<const float4*>(src)[o4];
  us4 s;
  s[0] = (u16)f2bf(f.x); s[1] = (u16)f2bf(f.y);
  s[2] = (u16)f2bf(f.z); s[3] = (u16)f2bf(f.w);
  reinterpret_cast<us4*>(wbf + (size_t)mat * C_ * C_)[o4] = s;
}

// ---------------------------------------------------------------------------
// KA: fused projection + context partial.
//   EK[d,n]=exp(kw·x+kb); V[c,n]=vw·x+vb (bf16 LDS stash);
//   part[kc][b][c][d]=sum_n V·EK;  zpart[kc][b][d]=sum_n EK
// grid (NC, B) = 256 blocks (1/CU), 512 thr = 8 waves, 128 KB LDS.
// x path: global->regs (coalesced dword, lane=n) -> cvtpk -> transposed
//   bf16 LDS tile xT[n][c] (XOR swizzle byte^=((n&7)<<4)), double-buffered.
//   All proj A-frags then = one conflict-free ds_read_b128 each.
// proj role: wave = (mat = w>>2, dblk = w&3 -> 32 d-rows), swapped MFMA
//   (A = xT rows n, B = W rows d) -> D[n][d], lane holds n-quad @ fixed d.
// ctx role: cg = w>>1 (32 c), dh = w&1 (64 d).
// Raw s_barrier + lgkmcnt-only waits: staged x loads (VMEM) stay in flight
// across barriers; next-subtile loads are issued a full subtile ahead.
// ---------------------------------------------------------------------------
#define KA_LOADS(ST_) do {                                                   \
  _Pragma("unroll") for (int h_ = 0; h_ < 2; ++h_)                           \
  _Pragma("unroll") for (int j_ = 0; j_ < 16; ++j_)                          \
    xr[h_][j_] = xw[(size_t)j_ * N_ + (ST_) * SN + h_ * 64 + lane];          \
} while (0)

#define KA_XWRITE(BUF_) do {                                                 \
  _Pragma("unroll") for (int h_ = 0; h_ < 2; ++h_) {                         \
    const int n_ = h_ * 64 + lane;                                           \
    unsigned pk_[8];                                                         \
    _Pragma("unroll") for (int p_ = 0; p_ < 8; ++p_)                         \
      pk_[p_] = cvtpk(xr[h_][2 * p_], xr[h_][2 * p_ + 1]);                   \
    _Pragma("unroll") for (int o_ = 0; o_ < 2; ++o_) {                       \
      uint4 q_;                                                              \
      q_.x = pk_[o_ * 4]; q_.y = pk_[o_ * 4 + 1];                            \
      q_.z = pk_[o_ * 4 + 2]; q_.w = pk_[o_ * 4 + 3];                        \
      *reinterpret_cast<uint4*>(                                             \
          (BUF_) + n_ * SN + ((w * 16 + o_ * 8) ^ ((n_ & 7) << 3))) = q_;    \
    }                                                                        \
  }                                                                          \
} while (0)

__global__ __launch_bounds__(512, 2) void ka_projctx(
    const float* __restrict__ kv, const u16* __restrict__ wbf,
    const float* __restrict__ kb, const float* __restrict__ vb,
    float* __restrict__ part, float* __restrict__ zpart) {
  __shared__ u16 xt[2][C_ * SN];   // 2 x 32 KB transposed bf16 x
  __shared__ u16 eks[C_ * SN];     // 32 KB EK stash [d][n]
  __shared__ u16 vs [C_ * SN];     // 32 KB V  stash [c][n]

  const int b = blockIdx.y, kc = blockIdx.x;
  const int tid = threadIdx.x;
  const int w = tid >> 6, lane = tid & 63;
  const int lg = lane >> 4, li = lane & 15;
  const int mat = w >> 2, dblk = w & 3;
  const int cg = w >> 1, dh = w & 1;

  const float* xb = kv + (size_t)b * C_ * N_ + (size_t)kc * CHN;
  const float* xw = xb + (size_t)(w * 16) * N_;  // wave's 16 c-rows
  const u16* Wm = wbf + (size_t)mat * C_ * C_;
  const float* biasp = mat ? vb : kb;
  u16* S = mat ? vs : eks;

  // W fragments (B-operand rows d) + bias, registers (L2-hot)
  short8 wreg[2][4];
#pragma unroll
  for (int dt = 0; dt < 2; ++dt)
#pragma unroll
    for (int ks = 0; ks < 4; ++ks)
      wreg[dt][ks] = *reinterpret_cast<const short8*>(
          Wm + (dblk * 32 + dt * 16 + li) * C_ + ks * 32 + lg * 8);
  float bias2[2];
#pragma unroll
  for (int dt = 0; dt < 2; ++dt) bias2[dt] = biasp[dblk * 32 + dt * 16 + li];

  f32x4 acc[2][4] = {};   // ctx accumulator [am c][dt d]
  float zac[2] = {0.f, 0.f};
  float xr[2][16];        // reg-staged x: [n-half][c-row j]

  // prologue: x(0) -> xT[0]; issue x(1)
  KA_LOADS(0);
  KA_XWRITE(&xt[0][0]);
  KA_LOADS(1);
  asm volatile("s_waitcnt lgkmcnt(0)" ::: "memory");
  __builtin_amdgcn_s_barrier();
  __builtin_amdgcn_sched_barrier(0);

#pragma unroll
  for (int st = 0; st < NST; ++st) {
    const u16* xc = &xt[st & 1][0];

    // transpose-write next subtile (regs already loaded), issue st+2 loads
    if (st < NST - 1) {
      KA_XWRITE(&xt[(st + 1) & 1][0]);
      if (st < NST - 2) KA_LOADS(st + 2);
    }

    // ---- proj: D[n][d] = xT · W^T, in nt-pairs ----
#pragma unroll
    for (int h2 = 0; h2 < 4; ++h2) {
      f32x4 pacc[2][2] = {};  // [ntl][dt]
#pragma unroll
      for (int ntl = 0; ntl < 2; ++ntl) {
        const int n = (h2 * 2 + ntl) * 16 + li;
#pragma unroll
        for (int ks = 0; ks < 4; ++ks) {
          short8 a = *reinterpret_cast<const short8*>(
              xc + n * SN + ((ks * 32 + lg * 8) ^ ((n & 7) << 3)));
#pragma unroll
          for (int dt = 0; dt < 2; ++dt)
            pacc[ntl][dt] = __builtin_amdgcn_mfma_f32_16x16x32_bf16(
                a, wreg[dt][ks], pacc[ntl][dt], 0, 0, 0);
        }
      }
      // bias (+exp for EK), pack, stash
#pragma unroll
      for (int dt = 0; dt < 2; ++dt) {
        const int d = dblk * 32 + dt * 16 + li;
        const float bias = bias2[dt];
#pragma unroll
        for (int ntl = 0; ntl < 2; ++ntl) {
          float v0 = pacc[ntl][dt][0] + bias;
          float v1 = pacc[ntl][dt][1] + bias;
          float v2 = pacc[ntl][dt][2] + bias;
          float v3 = pacc[ntl][dt][3] + bias;
          if (mat == 0) {
            v0 = __expf(v0); v1 = __expf(v1); v2 = __expf(v2); v3 = __expf(v3);
            zac[dt] += (v0 + v1) + (v2 + v3);
          }
          const int nq = (h2 * 2 + ntl) * 16 + lg * 4;
          uint2 pk; pk.x = cvtpk(v0, v1); pk.y = cvtpk(v2, v3);
          *reinterpret_cast<uint2*>(S + d * SN + (nq ^ ((d & 7) << 3))) = pk;
        }
      }
    }
    asm volatile("s_waitcnt lgkmcnt(0)" ::: "memory");
    __builtin_amdgcn_s_barrier();
    __builtin_amdgcn_sched_barrier(0);

    // ---- ctx: part += V·EK^T over this subtile's 128 n ----
#pragma unroll
    for (int kk = 0; kk < 4; ++kk) {
      const int n0 = kk * 32 + lg * 8;
      short8 a[2], bb[4];
#pragma unroll
      for (int am = 0; am < 2; ++am) {
        const int c = cg * 32 + am * 16 + li;
        a[am] = *reinterpret_cast<const short8*>(vs + c * SN + (n0 ^ ((c & 7) << 3)));
      }
#pragma unroll
      for (int dt = 0; dt < 4; ++dt) {
        const int d = dh * 64 + dt * 16 + li;
        bb[dt] = *reinterpret_cast<const short8*>(eks + d * SN + (n0 ^ ((d & 7) << 3)));
      }
#pragma unroll
      for (int am = 0; am < 2; ++am)
#pragma unroll
        for (int dt = 0; dt < 4; ++dt)
          acc[am][dt] = __builtin_amdgcn_mfma_f32_16x16x32_bf16(a[am], bb[dt], acc[am][dt], 0, 0, 0);
    }
    asm volatile("s_waitcnt lgkmcnt(0)" ::: "memory");
    __builtin_amdgcn_s_barrier();
    __builtin_amdgcn_sched_barrier(0);
  }

  // ---- epilogue: part + zpart (deterministic, no atomics) ----
  float* P = part + ((size_t)kc * B_ + b) * C_ * C_;
#pragma unroll
  for (int am = 0; am < 2; ++am)
#pragma unroll
    for (int dt = 0; dt < 4; ++dt)
#pragma unroll
      for (int r = 0; r < 4; ++r) {
        const int c = cg * 32 + am * 16 + lg * 4 + r;
        const int d = dh * 64 + dt * 16 + li;
        P[c * C_ + d] = acc[am][dt][r];
      }
  if (mat == 0) {
#pragma unroll
    for (int dt = 0; dt < 2; ++dt) {
      float z = zac[dt];
      z += __shfl_xor(z, 16);
      z += __shfl_xor(z, 32);
      if (lg == 0)
        zpart[((size_t)kc * B_ + b) * C_ + dblk * 32 + dt * 16 + li] = z;
    }
  }
}

// ---------------------------------------------------------------------------
// KB1: Psum[b] = sum_kc part[kc][b]   grid (32, B), 128 thr
// ---------------------------------------------------------------------------
__global__ __launch_bounds__(128) void kb1_red(const float* __restrict__ part,
                                               float* __restrict__ Psum) {
  const int g = blockIdx.x, b = blockIdx.y, t = threadIdx.x;
  const float4* P4 = reinterpret_cast<const float4*>(part);
  float ax = 0.f, ay = 0.f, az = 0.f, aw = 0.f;
#pragma unroll 4
  for (int kc = 0; kc < NC; ++kc) {
    float4 v = P4[((size_t)kc * B_ + b) * 4096 + g * 128 + t];
    ax += v.x; ay += v.y; az += v.z; aw += v.w;
  }
  float4 o; o.x = ax; o.y = ay; o.z = az; o.w = aw;
  reinterpret_cast<float4*>(Psum)[(size_t)b * 4096 + g * 128 + t] = o;
}

// ---------------------------------------------------------------------------
// KB2: cs = Psum/Z ; M = cs·qw (bf16), T = cs·qb
// grid (8, B), 256 thr; block owns 16 c-rows.
// ---------------------------------------------------------------------------
__global__ __launch_bounds__(256) void kb2_fin(
    const float* __restrict__ Psum, const float* __restrict__ zpart,
    const float* __restrict__ qw, const float* __restrict__ qb,
    u16* __restrict__ M, float* __restrict__ T) {
  const int b = blockIdx.y;
  const int cs0 = blockIdx.x * 16;
  const int tid = threadIdx.x;
  __shared__ float cs[16][128];
  __shared__ float Zs[128];
  if (tid < 128) {
    float s = 0.f;
    for (int kc = 0; kc < NC; ++kc)
      s += zpart[((size_t)kc * B_ + b) * C_ + tid];
    Zs[tid] = s;
  }
  __syncthreads();
#pragma unroll
  for (int i = 0; i < 8; ++i) {
    const int e = tid + i * 256;
    const int cl = e >> 7, d = e & 127;
    cs[cl][d] = Psum[((size_t)b * C_ + cs0 + cl) * C_ + d] / Zs[d];
  }
  __syncthreads();
  const int cl = tid >> 4, e0 = (tid & 15) * 8;
  float m[8] = {};
  for (int d = 0; d < 128; ++d) {
    const float cv = cs[cl][d];
    const float* qr = qw + d * C_ + e0;
#pragma unroll
    for (int j = 0; j < 8; ++j) m[j] += cv * qr[j];
  }
  u16* mp = M + ((size_t)b * C_ + cs0 + cl) * C_ + e0;
#pragma unroll
  for (int j = 0; j < 8; ++j) mp[j] = (u16)f2bf(m[j]);
  if (tid < 16) {
    float tv = 0.f;
    for (int d = 0; d < 128; ++d) tv += cs[tid][d] * qb[d];
    T[b * C_ + cs0 + tid] = tv;
  }
}

// ---------------------------------------------------------------------------
// K4: out = M·q_feat + T (fp32).  grid (N/64, B), 256 thr = 4 waves.
// Swapped-operand MFMA -> D[n][c]: float4 stores.  M in registers.
// ---------------------------------------------------------------------------
__global__ __launch_bounds__(256) void k4_out(const u16* __restrict__ M,
                                              const float* __restrict__ T,
                                              const float* __restrict__ q,
                                              float* __restrict__ out) {
  __shared__ float qs[C_ * SN4];  // [d][64] fp32 swizzled, 32 KB
  const int b = blockIdx.y;
  const int n0 = blockIdx.x * 64;
  const int tid = threadIdx.x;
  const int w = tid >> 6, lane = tid & 63;
  const int lg = lane >> 4, li = lane & 15;
  const int r_in = lane >> 4, slot = lane & 15;

  const float* qbp = q + (size_t)b * C_ * N_ + n0;
#pragma unroll
  for (int i = 0; i < 8; ++i) {
    const int row = w * 32 + i * 4 + r_in;
    gl_lds16(qbp + (size_t)row * N_ + 4 * (slot ^ swz(row)), qs + (w * 32 + i * 4) * SN4);
  }

  short8 mreg[2][4];
  const u16* Mb = M + (size_t)b * C_ * C_;
#pragma unroll
  for (int ct = 0; ct < 2; ++ct)
#pragma unroll
    for (int ks = 0; ks < 4; ++ks)
      mreg[ct][ks] = *reinterpret_cast<const short8*>(
          Mb + (w * 32 + ct * 16 + li) * C_ + ks * 32 + lg * 8);
  float tc[2];
#pragma unroll
  for (int ct = 0; ct < 2; ++ct) tc[ct] = T[b * C_ + w * 32 + ct * 16 + li];

  __syncthreads();

  f32x4 acc[2][4] = {};  // [ct][nt]
#pragma unroll
  for (int nt = 0; nt < 4; ++nt) {
    const int n = nt * 16 + li;
#pragma unroll
    for (int ks = 0; ks < 4; ++ks) {
      SB sb;
#pragma unroll
      for (int p = 0; p < 4; ++p) {
        const int d0 = ks * 32 + lg * 8 + 2 * p;
        const float f0 = qs[d0 * SN4 + (n ^ (swz(d0) << 2))];
        const float f1 = qs[(d0 + 1) * SN4 + (n ^ (swz(d0 + 1) << 2))];
        sb.u[p] = cvtpk(f0, f1);
      }
#pragma unroll
      for (int ct = 0; ct < 2; ++ct)
        acc[ct][nt] = __builtin_amdgcn_mfma_f32_16x16x32_bf16(sb.s8, mreg[ct][ks], acc[ct][nt], 0, 0, 0);
    }
  }

#pragma unroll
  for (int ct = 0; ct < 2; ++ct) {
    const int c = w * 32 + ct * 16 + li;
    float* op = out + ((size_t)b * C_ + c) * N_ + n0;
#pragma unroll
    for (int nt = 0; nt < 4; ++nt) {
      float4 v;
      v.x = acc[ct][nt][0] + tc[ct];
      v.y = acc[ct][nt][1] + tc[ct];
      v.z = acc[ct][nt][2] + tc[ct];
      v.w = acc[ct][nt][3] + tc[ct];
      *reinterpret_cast<float4*>(op + nt * 16 + lg * 4) = v;
    }
  }
}

// ---------------------------------------------------------------------------
extern "C" void kernel_launch(void* const* d_in, const int* in_sizes, int n_in,
                              void* d_out, int out_size, void* d_ws, size_t ws_size,
                              hipStream_t stream) {
  const float* q_feat  = (const float*)d_in[0];
  const float* kv_feat = (const float*)d_in[1];
  const float* q_w = (const float*)d_in[2];
  const float* q_b = (const float*)d_in[3];
  const float* k_w = (const float*)d_in[4];
  const float* k_b = (const float*)d_in[5];
  const float* v_w = (const float*)d_in[6];
  const float* v_b = (const float*)d_in[7];
  float* out = (float*)d_out;

  char* ws = (char*)d_ws;
  const size_t szPart = (size_t)NC * B_ * C_ * C_ * sizeof(float);  // 16 MB
  const size_t szZp   = (size_t)NC * B_ * C_ * sizeof(float);       // 128 KB
  const size_t szPs   = (size_t)B_ * C_ * C_ * sizeof(float);       // 512 KB
  const size_t szWbf  = (size_t)2 * C_ * C_ * sizeof(u16);          // 64 KB
  const size_t szM    = (size_t)B_ * C_ * C_ * sizeof(u16);         // 256 KB

  float* part  = (float*)ws;
  float* zpart = (float*)(ws + szPart);
  float* Psum  = (float*)(ws + szPart + szZp);
  u16*   wbf   = (u16*)(ws + szPart + szZp + szPs);
  u16*   M     = (u16*)(ws + szPart + szZp + szPs + szWbf);
  float* T     = (float*)(ws + szPart + szZp + szPs + szWbf + szM);

  k0_wcvt<<<dim3(32), 256, 0, stream>>>(k_w, v_w, wbf);
  ka_projctx<<<dim3(NC, B_), 512, 0, stream>>>(kv_feat, wbf, k_b, v_b, part, zpart);
  kb1_red<<<dim3(32, B_), 128, 0, stream>>>(part, Psum);
  kb2_fin<<<dim3(8, B_), 256, 0, stream>>>(Psum, zpart, q_w, q_b, M, T);
  k4_out<<<dim3(N_ / SN4, B_), 256, 0, stream>>>(M, T, q_feat, out);
}

// Round 8
// 76.217 us; speedup vs baseline: 2.0319x; 1.0351x over previous
//
#include <hip/hip_runtime.h>
#include <hip/hip_bf16.h>
#include <cstdint>

#define B_ 8
#define C_ 128
#define N_ 16384   // H*W
#define CHN 512    // n per KA block
#define SN 128     // n per KA subtile
#define NST 4      // subtiles per KA block
#define NC (N_ / CHN)  // 32 chunks
#define SN4 64     // n per K4 block

typedef __attribute__((ext_vector_type(8))) short short8;
typedef __attribute__((ext_vector_type(4))) float f32x4;
typedef __attribute__((ext_vector_type(4))) unsigned short us4;
typedef unsigned short u16;

__device__ __forceinline__ short f2bf(float f) {
  union { float f; unsigned u; } c; c.f = f;
  unsigned r = (c.u + 0x7FFFu + ((c.u >> 16) & 1u)) >> 16;
  return (short)r;
}

__device__ __forceinline__ unsigned cvtpk(float lo, float hi) {
  unsigned r;
  asm("v_cvt_pk_bf16_f32 %0, %1, %2" : "=v"(r) : "v"(lo), "v"(hi));
  return r;
}

union SB { short8 s8; unsigned u[4]; };

__device__ __forceinline__ void gl_lds16(const float* g, float* l) {
  __builtin_amdgcn_global_load_lds(
      (const __attribute__((address_space(1))) void*)g,
      (__attribute__((address_space(3))) void*)l, 16, 0, 0);
}

// slot swizzle for fp32 [row][64] tiles (K4 staging)
__device__ __forceinline__ int swz(int row) { return (row ^ (row >> 2)) & 7; }

// ---------------------------------------------------------------------------
// K0: preconvert k_w, v_w (fp32) -> wbf (bf16 [2][128][128])
// ---------------------------------------------------------------------------
__global__ __launch_bounds__(256) void k0_wcvt(const float* __restrict__ kw,
                                               const float* __restrict__ vw,
                                               u16* __restrict__ wbf) {
  const int g = blockIdx.x * 256 + threadIdx.x;  // 0..8191 float4s
  const int mat = g >> 12, o4 = g & 4095;
  const float* src = mat ? vw : kw;
  float4 f = reinterpret_cast<const float4*>(src)[o4];
  us4 s;
  s[0] = (u16)f2bf(f.x); s[1] = (u16)f2bf(f.y);
  s[2] = (u16)f2bf(f.z); s[3] = (u16)f2bf(f.w);
  reinterpret_cast<us4*>(wbf + (size_t)mat * C_ * C_)[o4] = s;
}

// ---------------------------------------------------------------------------
// KA: fused projection + context partial (unchanged from round 6, which
// passed with absmax 0.03125).
// ---------------------------------------------------------------------------
#define KA_LOADS(ST_) do {                                                   \
  _Pragma("unroll") for (int h_ = 0; h_ < 2; ++h_)                           \
  _Pragma("unroll") for (int j_ = 0; j_ < 16; ++j_)                          \
    xr[h_][j_] = xw[(size_t)j_ * N_ + (ST_) * SN + h_ * 64 + lane];          \
} while (0)

#define KA_XWRITE(BUF_) do {                                                 \
  _Pragma("unroll") for (int h_ = 0; h_ < 2; ++h_) {                         \
    const int n_ = h_ * 64 + lane;                                           \
    unsigned pk_[8];                                                         \
    _Pragma("unroll") for (int p_ = 0; p_ < 8; ++p_)                         \
      pk_[p_] = cvtpk(xr[h_][2 * p_], xr[h_][2 * p_ + 1]);                   \
    _Pragma("unroll") for (int o_ = 0; o_ < 2; ++o_) {                       \
      uint4 q_;                                                              \
      q_.x = pk_[o_ * 4]; q_.y = pk_[o_ * 4 + 1];                            \
      q_.z = pk_[o_ * 4 + 2]; q_.w = pk_[o_ * 4 + 3];                        \
      *reinterpret_cast<uint4*>(                                             \
          (BUF_) + n_ * SN + ((w * 16 + o_ * 8) ^ ((n_ & 7) << 3))) = q_;    \
    }                                                                        \
  }                                                                          \
} while (0)

__global__ __launch_bounds__(512, 2) void ka_projctx(
    const float* __restrict__ kv, const u16* __restrict__ wbf,
    const float* __restrict__ kb, const float* __restrict__ vb,
    float* __restrict__ part, float* __restrict__ zpart) {
  __shared__ u16 xt[2][C_ * SN];   // 2 x 32 KB transposed bf16 x
  __shared__ u16 eks[C_ * SN];     // 32 KB EK stash [d][n]
  __shared__ u16 vs [C_ * SN];     // 32 KB V  stash [c][n]

  const int b = blockIdx.y, kc = blockIdx.x;
  const int tid = threadIdx.x;
  const int w = tid >> 6, lane = tid & 63;
  const int lg = lane >> 4, li = lane & 15;
  const int mat = w >> 2, dblk = w & 3;
  const int cg = w >> 1, dh = w & 1;

  const float* xb = kv + (size_t)b * C_ * N_ + (size_t)kc * CHN;
  const float* xw = xb + (size_t)(w * 16) * N_;  // wave's 16 c-rows
  const u16* Wm = wbf + (size_t)mat * C_ * C_;
  const float* biasp = mat ? vb : kb;
  u16* S = mat ? vs : eks;

  short8 wreg[2][4];
#pragma unroll
  for (int dt = 0; dt < 2; ++dt)
#pragma unroll
    for (int ks = 0; ks < 4; ++ks)
      wreg[dt][ks] = *reinterpret_cast<const short8*>(
          Wm + (dblk * 32 + dt * 16 + li) * C_ + ks * 32 + lg * 8);
  float bias2[2];
#pragma unroll
  for (int dt = 0; dt < 2; ++dt) bias2[dt] = biasp[dblk * 32 + dt * 16 + li];

  f32x4 acc[2][4] = {};   // ctx accumulator [am c][dt d]
  float zac[2] = {0.f, 0.f};
  float xr[2][16];        // reg-staged x: [n-half][c-row j]

  KA_LOADS(0);
  KA_XWRITE(&xt[0][0]);
  KA_LOADS(1);
  asm volatile("s_waitcnt lgkmcnt(0)" ::: "memory");
  __builtin_amdgcn_s_barrier();
  __builtin_amdgcn_sched_barrier(0);

#pragma unroll
  for (int st = 0; st < NST; ++st) {
    const u16* xc = &xt[st & 1][0];

    if (st < NST - 1) {
      KA_XWRITE(&xt[(st + 1) & 1][0]);
      if (st < NST - 2) KA_LOADS(st + 2);
    }

    // ---- proj: D[n][d] = xT · W^T, in nt-pairs ----
#pragma unroll
    for (int h2 = 0; h2 < 4; ++h2) {
      f32x4 pacc[2][2] = {};  // [ntl][dt]
#pragma unroll
      for (int ntl = 0; ntl < 2; ++ntl) {
        const int n = (h2 * 2 + ntl) * 16 + li;
#pragma unroll
        for (int ks = 0; ks < 4; ++ks) {
          short8 a = *reinterpret_cast<const short8*>(
              xc + n * SN + ((ks * 32 + lg * 8) ^ ((n & 7) << 3)));
#pragma unroll
          for (int dt = 0; dt < 2; ++dt)
            pacc[ntl][dt] = __builtin_amdgcn_mfma_f32_16x16x32_bf16(
                a, wreg[dt][ks], pacc[ntl][dt], 0, 0, 0);
        }
      }
#pragma unroll
      for (int dt = 0; dt < 2; ++dt) {
        const int d = dblk * 32 + dt * 16 + li;
        const float bias = bias2[dt];
#pragma unroll
        for (int ntl = 0; ntl < 2; ++ntl) {
          float v0 = pacc[ntl][dt][0] + bias;
          float v1 = pacc[ntl][dt][1] + bias;
          float v2 = pacc[ntl][dt][2] + bias;
          float v3 = pacc[ntl][dt][3] + bias;
          if (mat == 0) {
            v0 = __expf(v0); v1 = __expf(v1); v2 = __expf(v2); v3 = __expf(v3);
            zac[dt] += (v0 + v1) + (v2 + v3);
          }
          const int nq = (h2 * 2 + ntl) * 16 + lg * 4;
          uint2 pk; pk.x = cvtpk(v0, v1); pk.y = cvtpk(v2, v3);
          *reinterpret_cast<uint2*>(S + d * SN + (nq ^ ((d & 7) << 3))) = pk;
        }
      }
    }
    asm volatile("s_waitcnt lgkmcnt(0)" ::: "memory");
    __builtin_amdgcn_s_barrier();
    __builtin_amdgcn_sched_barrier(0);

    // ---- ctx: part += V·EK^T over this subtile's 128 n ----
#pragma unroll
    for (int kk = 0; kk < 4; ++kk) {
      const int n0 = kk * 32 + lg * 8;
      short8 a[2], bb[4];
#pragma unroll
      for (int am = 0; am < 2; ++am) {
        const int c = cg * 32 + am * 16 + li;
        a[am] = *reinterpret_cast<const short8*>(vs + c * SN + (n0 ^ ((c & 7) << 3)));
      }
#pragma unroll
      for (int dt = 0; dt < 4; ++dt) {
        const int d = dh * 64 + dt * 16 + li;
        bb[dt] = *reinterpret_cast<const short8*>(eks + d * SN + (n0 ^ ((d & 7) << 3)));
      }
#pragma unroll
      for (int am = 0; am < 2; ++am)
#pragma unroll
        for (int dt = 0; dt < 4; ++dt)
          acc[am][dt] = __builtin_amdgcn_mfma_f32_16x16x32_bf16(a[am], bb[dt], acc[am][dt], 0, 0, 0);
    }
    asm volatile("s_waitcnt lgkmcnt(0)" ::: "memory");
    __builtin_amdgcn_s_barrier();
    __builtin_amdgcn_sched_barrier(0);
  }

  // ---- epilogue: part + zpart (deterministic, no atomics) ----
  float* P = part + ((size_t)kc * B_ + b) * C_ * C_;
#pragma unroll
  for (int am = 0; am < 2; ++am)
#pragma unroll
    for (int dt = 0; dt < 4; ++dt)
#pragma unroll
      for (int r = 0; r < 4; ++r) {
        const int c = cg * 32 + am * 16 + lg * 4 + r;
        const int d = dh * 64 + dt * 16 + li;
        P[c * C_ + d] = acc[am][dt][r];
      }
  if (mat == 0) {
#pragma unroll
    for (int dt = 0; dt < 2; ++dt) {
      float z = zac[dt];
      z += __shfl_xor(z, 16);
      z += __shfl_xor(z, 32);
      if (lg == 0)
        zpart[((size_t)kc * B_ + b) * C_ + dblk * 32 + dt * 16 + li] = z;
    }
  }
}

// ---------------------------------------------------------------------------
// KB2: cs = (sum_kc part)/Z ; M = cs·qw (bf16), T = cs·qb
// grid (8, B), 256 thr; block owns 16 c-rows.  (KB1 folded in; index algebra
// identical to round-3's proven k3_fin.)
// ---------------------------------------------------------------------------
__global__ __launch_bounds__(256) void kb2_fin(
    const float* __restrict__ part, const float* __restrict__ zpart,
    const float* __restrict__ qw, const float* __restrict__ qb,
    u16* __restrict__ M, float* __restrict__ T) {
  const int b = blockIdx.y;
  const int cs0 = blockIdx.x * 16;
  const int tid = threadIdx.x;
  __shared__ float cs[16][128];
  __shared__ float Zs[128];
  if (tid < 128) {
    float s = 0.f;
    for (int kc = 0; kc < NC; ++kc)
      s += zpart[((size_t)kc * B_ + b) * C_ + tid];
    Zs[tid] = s;
  }
  __syncthreads();
#pragma unroll
  for (int i = 0; i < 8; ++i) {
    const int e = tid + i * 256;
    const int cl = e >> 7, d = e & 127;
    float s = 0.f;
    for (int kc = 0; kc < NC; ++kc)
      s += part[(((size_t)kc * B_ + b) * C_ + (cs0 + cl)) * C_ + d];
    cs[cl][d] = s / Zs[d];
  }
  __syncthreads();
  const int cl = tid >> 4, e0 = (tid & 15) * 8;
  float m[8] = {};
  for (int d = 0; d < 128; ++d) {
    const float cv = cs[cl][d];
    const float* qr = qw + d * C_ + e0;
#pragma unroll
    for (int j = 0; j < 8; ++j) m[j] += cv * qr[j];
  }
  u16* mp = M + ((size_t)b * C_ + cs0 + cl) * C_ + e0;
#pragma unroll
  for (int j = 0; j < 8; ++j) mp[j] = (u16)f2bf(m[j]);
  if (tid < 16) {
    float tv = 0.f;
    for (int d = 0; d < 128; ++d) tv += cs[tid][d] * qb[d];
    T[b * C_ + cs0 + tid] = tv;
  }
}

// ---------------------------------------------------------------------------
// K4: out = M·q_feat + T (fp32).  grid (N/64, B), 256 thr = 4 waves.
// NON-swapped MFMA: A = M rows c, B = q cols n  ->  D[c][n]:
//   col (li) = n, row (lg*4+r) = c.  Stores are aligned 64-B row segments
//   (16 consecutive lanes per c-row) — no LDS epilogue, no extra barrier.
// Same fragment registers and same dot products as round 6 (A/B operand
// lane layouts are identical on gfx950), so numerics match round 6.
// ---------------------------------------------------------------------------
__global__ __launch_bounds__(256) void k4_out(const u16* __restrict__ M,
                                              const float* __restrict__ T,
                                              const float* __restrict__ q,
                                              float* __restrict__ out) {
  __shared__ float qs[C_ * SN4];  // [d][64] fp32 swizzled, 32 KB
  const int b = blockIdx.y;
  const int n0 = blockIdx.x * 64;
  const int tid = threadIdx.x;
  const int w = tid >> 6, lane = tid & 63;
  const int lg = lane >> 4, li = lane & 15;
  const int r_in = lane >> 4, slot = lane & 15;

  const float* qbp = q + (size_t)b * C_ * N_ + n0;
#pragma unroll
  for (int i = 0; i < 8; ++i) {
    const int row = w * 32 + i * 4 + r_in;
    gl_lds16(qbp + (size_t)row * N_ + 4 * (slot ^ swz(row)), qs + (w * 32 + i * 4) * SN4);
  }

  // M fragments (A operand, rows c) + T per output row (broadcast loads)
  short8 mreg[2][4];
  const u16* Mb = M + (size_t)b * C_ * C_;
#pragma unroll
  for (int ct = 0; ct < 2; ++ct)
#pragma unroll
    for (int ks = 0; ks < 4; ++ks)
      mreg[ct][ks] = *reinterpret_cast<const short8*>(
          Mb + (w * 32 + ct * 16 + li) * C_ + ks * 32 + lg * 8);
  float tcv[2][4];
#pragma unroll
  for (int ct = 0; ct < 2; ++ct)
#pragma unroll
    for (int r = 0; r < 4; ++r)
      tcv[ct][r] = T[b * C_ + w * 32 + ct * 16 + lg * 4 + r];

  __syncthreads();

  f32x4 acc[2][4] = {};  // [ct][nt];  D[c][n]: c = lg*4+r, n = nt*16+li
#pragma unroll
  for (int nt = 0; nt < 4; ++nt) {
    const int n = nt * 16 + li;
#pragma unroll
    for (int ks = 0; ks < 4; ++ks) {
      SB sb;
#pragma unroll
      for (int p = 0; p < 4; ++p) {
        const int d0 = ks * 32 + lg * 8 + 2 * p;
        const float f0 = qs[d0 * SN4 + (n ^ (swz(d0) << 2))];
        const float f1 = qs[(d0 + 1) * SN4 + (n ^ (swz(d0 + 1) << 2))];
        sb.u[p] = cvtpk(f0, f1);
      }
#pragma unroll
      for (int ct = 0; ct < 2; ++ct)
        acc[ct][nt] = __builtin_amdgcn_mfma_f32_16x16x32_bf16(mreg[ct][ks], sb.s8, acc[ct][nt], 0, 0, 0);
    }
  }

  // stores: per (ct,r): c-row = w*32+ct*16+lg*4+r; 16 lanes (li) write 64 B
#pragma unroll
  for (int ct = 0; ct < 2; ++ct)
#pragma unroll
    for (int r = 0; r < 4; ++r) {
      const int c = w * 32 + ct * 16 + lg * 4 + r;
      float* op = out + ((size_t)b * C_ + c) * N_ + n0;
      const float t = tcv[ct][r];
#pragma unroll
      for (int nt = 0; nt < 4; ++nt)
        op[nt * 16 + li] = acc[ct][nt][r] + t;
    }
}

// ---------------------------------------------------------------------------
extern "C" void kernel_launch(void* const* d_in, const int* in_sizes, int n_in,
                              void* d_out, int out_size, void* d_ws, size_t ws_size,
                              hipStream_t stream) {
  const float* q_feat  = (const float*)d_in[0];
  const float* kv_feat = (const float*)d_in[1];
  const float* q_w = (const float*)d_in[2];
  const float* q_b = (const float*)d_in[3];
  const float* k_w = (const float*)d_in[4];
  const float* k_b = (const float*)d_in[5];
  const float* v_w = (const float*)d_in[6];
  const float* v_b = (const float*)d_in[7];
  float* out = (float*)d_out;

  char* ws = (char*)d_ws;
  const size_t szPart = (size_t)NC * B_ * C_ * C_ * sizeof(float);  // 16 MB
  const size_t szZp   = (size_t)NC * B_ * C_ * sizeof(float);       // 128 KB
  const size_t szWbf  = (size_t)2 * C_ * C_ * sizeof(u16);          // 64 KB
  const size_t szM    = (size_t)B_ * C_ * C_ * sizeof(u16);         // 256 KB

  float* part  = (float*)ws;
  float* zpart = (float*)(ws + szPart);
  u16*   wbf   = (u16*)(ws + szPart + szZp);
  u16*   M     = (u16*)(ws + szPart + szZp + szWbf);
  float* T     = (float*)(ws + szPart + szZp + szWbf + szM);

  k0_wcvt<<<dim3(32), 256, 0, stream>>>(k_w, v_w, wbf);
  ka_projctx<<<dim3(NC, B_), 512, 0, stream>>>(kv_feat, wbf, k_b, v_b, part, zpart);
  kb2_fin<<<dim3(8, B_), 256, 0, stream>>>(part, zpart, q_w, q_b, M, T);
  k4_out<<<dim3(N_ / SN4, B_), 256, 0, stream>>>(M, T, q_feat, out);
}

// Round 9
// 75.797 us; speedup vs baseline: 2.0432x; 1.0055x over previous
//
#include <hip/hip_runtime.h>
#include <hip/hip_bf16.h>
#include <cstdint>

#define B_ 8
#define C_ 128
#define N_ 16384   // H*W
#define CHN 512    // n per KA block
#define SN 128     // n per KA subtile
#define NST 4      // subtiles per KA block
#define NC (N_ / CHN)  // 32 chunks
#define SN4 64     // n per K4 block

typedef __attribute__((ext_vector_type(8))) short short8;
typedef __attribute__((ext_vector_type(4))) float f32x4;
typedef __attribute__((ext_vector_type(4))) unsigned short us4;
typedef unsigned short u16;

__device__ __forceinline__ short f2bf(float f) {
  union { float f; unsigned u; } c; c.f = f;
  unsigned r = (c.u + 0x7FFFu + ((c.u >> 16) & 1u)) >> 16;
  return (short)r;
}

__device__ __forceinline__ unsigned cvtpk(float lo, float hi) {
  unsigned r;
  asm("v_cvt_pk_bf16_f32 %0, %1, %2" : "=v"(r) : "v"(lo), "v"(hi));
  return r;
}

union SB { short8 s8; unsigned u[4]; };

// ---------------------------------------------------------------------------
// K0: preconvert k_w, v_w (fp32) -> wbf (bf16 [2][128][128])
// ---------------------------------------------------------------------------
__global__ __launch_bounds__(256) void k0_wcvt(const float* __restrict__ kw,
                                               const float* __restrict__ vw,
                                               u16* __restrict__ wbf) {
  const int g = blockIdx.x * 256 + threadIdx.x;  // 0..8191 float4s
  const int mat = g >> 12, o4 = g & 4095;
  const float* src = mat ? vw : kw;
  float4 f = reinterpret_cast<const float4*>(src)[o4];
  us4 s;
  s[0] = (u16)f2bf(f.x); s[1] = (u16)f2bf(f.y);
  s[2] = (u16)f2bf(f.z); s[3] = (u16)f2bf(f.w);
  reinterpret_cast<us4*>(wbf + (size_t)mat * C_ * C_)[o4] = s;
}

// ---------------------------------------------------------------------------
// KA: fused projection + context partial (unchanged from round 6/8; passed
// with absmax 0.03125).
// ---------------------------------------------------------------------------
#define KA_LOADS(ST_) do {                                                   \
  _Pragma("unroll") for (int h_ = 0; h_ < 2; ++h_)                           \
  _Pragma("unroll") for (int j_ = 0; j_ < 16; ++j_)                          \
    xr[h_][j_] = xw[(size_t)j_ * N_ + (ST_) * SN + h_ * 64 + lane];          \
} while (0)

#define KA_XWRITE(BUF_) do {                                                 \
  _Pragma("unroll") for (int h_ = 0; h_ < 2; ++h_) {                         \
    const int n_ = h_ * 64 + lane;                                           \
    unsigned pk_[8];                                                         \
    _Pragma("unroll") for (int p_ = 0; p_ < 8; ++p_)                         \
      pk_[p_] = cvtpk(xr[h_][2 * p_], xr[h_][2 * p_ + 1]);                   \
    _Pragma("unroll") for (int o_ = 0; o_ < 2; ++o_) {                       \
      uint4 q_;                                                              \
      q_.x = pk_[o_ * 4]; q_.y = pk_[o_ * 4 + 1];                            \
      q_.z = pk_[o_ * 4 + 2]; q_.w = pk_[o_ * 4 + 3];                        \
      *reinterpret_cast<uint4*>(                                             \
          (BUF_) + n_ * SN + ((w * 16 + o_ * 8) ^ ((n_ & 7) << 3))) = q_;    \
    }                                                                        \
  }                                                                          \
} while (0)

__global__ __launch_bounds__(512, 2) void ka_projctx(
    const float* __restrict__ kv, const u16* __restrict__ wbf,
    const float* __restrict__ kb, const float* __restrict__ vb,
    float* __restrict__ part, float* __restrict__ zpart) {
  __shared__ u16 xt[2][C_ * SN];   // 2 x 32 KB transposed bf16 x
  __shared__ u16 eks[C_ * SN];     // 32 KB EK stash [d][n]
  __shared__ u16 vs [C_ * SN];     // 32 KB V  stash [c][n]

  const int b = blockIdx.y, kc = blockIdx.x;
  const int tid = threadIdx.x;
  const int w = tid >> 6, lane = tid & 63;
  const int lg = lane >> 4, li = lane & 15;
  const int mat = w >> 2, dblk = w & 3;
  const int cg = w >> 1, dh = w & 1;

  const float* xb = kv + (size_t)b * C_ * N_ + (size_t)kc * CHN;
  const float* xw = xb + (size_t)(w * 16) * N_;  // wave's 16 c-rows
  const u16* Wm = wbf + (size_t)mat * C_ * C_;
  const float* biasp = mat ? vb : kb;
  u16* S = mat ? vs : eks;

  short8 wreg[2][4];
#pragma unroll
  for (int dt = 0; dt < 2; ++dt)
#pragma unroll
    for (int ks = 0; ks < 4; ++ks)
      wreg[dt][ks] = *reinterpret_cast<const short8*>(
          Wm + (dblk * 32 + dt * 16 + li) * C_ + ks * 32 + lg * 8);
  float bias2[2];
#pragma unroll
  for (int dt = 0; dt < 2; ++dt) bias2[dt] = biasp[dblk * 32 + dt * 16 + li];

  f32x4 acc[2][4] = {};   // ctx accumulator [am c][dt d]
  float zac[2] = {0.f, 0.f};
  float xr[2][16];        // reg-staged x: [n-half][c-row j]

  KA_LOADS(0);
  KA_XWRITE(&xt[0][0]);
  KA_LOADS(1);
  asm volatile("s_waitcnt lgkmcnt(0)" ::: "memory");
  __builtin_amdgcn_s_barrier();
  __builtin_amdgcn_sched_barrier(0);

#pragma unroll
  for (int st = 0; st < NST; ++st) {
    const u16* xc = &xt[st & 1][0];

    if (st < NST - 1) {
      KA_XWRITE(&xt[(st + 1) & 1][0]);
      if (st < NST - 2) KA_LOADS(st + 2);
    }

    // ---- proj: D[n][d] = xT · W^T, in nt-pairs ----
#pragma unroll
    for (int h2 = 0; h2 < 4; ++h2) {
      f32x4 pacc[2][2] = {};  // [ntl][dt]
#pragma unroll
      for (int ntl = 0; ntl < 2; ++ntl) {
        const int n = (h2 * 2 + ntl) * 16 + li;
#pragma unroll
        for (int ks = 0; ks < 4; ++ks) {
          short8 a = *reinterpret_cast<const short8*>(
              xc + n * SN + ((ks * 32 + lg * 8) ^ ((n & 7) << 3)));
#pragma unroll
          for (int dt = 0; dt < 2; ++dt)
            pacc[ntl][dt] = __builtin_amdgcn_mfma_f32_16x16x32_bf16(
                a, wreg[dt][ks], pacc[ntl][dt], 0, 0, 0);
        }
      }
#pragma unroll
      for (int dt = 0; dt < 2; ++dt) {
        const int d = dblk * 32 + dt * 16 + li;
        const float bias = bias2[dt];
#pragma unroll
        for (int ntl = 0; ntl < 2; ++ntl) {
          float v0 = pacc[ntl][dt][0] + bias;
          float v1 = pacc[ntl][dt][1] + bias;
          float v2 = pacc[ntl][dt][2] + bias;
          float v3 = pacc[ntl][dt][3] + bias;
          if (mat == 0) {
            v0 = __expf(v0); v1 = __expf(v1); v2 = __expf(v2); v3 = __expf(v3);
            zac[dt] += (v0 + v1) + (v2 + v3);
          }
          const int nq = (h2 * 2 + ntl) * 16 + lg * 4;
          uint2 pk; pk.x = cvtpk(v0, v1); pk.y = cvtpk(v2, v3);
          *reinterpret_cast<uint2*>(S + d * SN + (nq ^ ((d & 7) << 3))) = pk;
        }
      }
    }
    asm volatile("s_waitcnt lgkmcnt(0)" ::: "memory");
    __builtin_amdgcn_s_barrier();
    __builtin_amdgcn_sched_barrier(0);

    // ---- ctx: part += V·EK^T over this subtile's 128 n ----
#pragma unroll
    for (int kk = 0; kk < 4; ++kk) {
      const int n0 = kk * 32 + lg * 8;
      short8 a[2], bb[4];
#pragma unroll
      for (int am = 0; am < 2; ++am) {
        const int c = cg * 32 + am * 16 + li;
        a[am] = *reinterpret_cast<const short8*>(vs + c * SN + (n0 ^ ((c & 7) << 3)));
      }
#pragma unroll
      for (int dt = 0; dt < 4; ++dt) {
        const int d = dh * 64 + dt * 16 + li;
        bb[dt] = *reinterpret_cast<const short8*>(eks + d * SN + (n0 ^ ((d & 7) << 3)));
      }
#pragma unroll
      for (int am = 0; am < 2; ++am)
#pragma unroll
        for (int dt = 0; dt < 4; ++dt)
          acc[am][dt] = __builtin_amdgcn_mfma_f32_16x16x32_bf16(a[am], bb[dt], acc[am][dt], 0, 0, 0);
    }
    asm volatile("s_waitcnt lgkmcnt(0)" ::: "memory");
    __builtin_amdgcn_s_barrier();
    __builtin_amdgcn_sched_barrier(0);
  }

  // ---- epilogue: part + zpart (deterministic, no atomics) ----
  float* P = part + ((size_t)kc * B_ + b) * C_ * C_;
#pragma unroll
  for (int am = 0; am < 2; ++am)
#pragma unroll
    for (int dt = 0; dt < 4; ++dt)
#pragma unroll
      for (int r = 0; r < 4; ++r) {
        const int c = cg * 32 + am * 16 + lg * 4 + r;
        const int d = dh * 64 + dt * 16 + li;
        P[c * C_ + d] = acc[am][dt][r];
      }
  if (mat == 0) {
#pragma unroll
    for (int dt = 0; dt < 2; ++dt) {
      float z = zac[dt];
      z += __shfl_xor(z, 16);
      z += __shfl_xor(z, 32);
      if (lg == 0)
        zpart[((size_t)kc * B_ + b) * C_ + dblk * 32 + dt * 16 + li] = z;
    }
  }
}

// ---------------------------------------------------------------------------
// KB2: cs = (sum_kc part)/Z ; M = cs·qw (bf16), T = cs·qb
// (unchanged from round 8)
// ---------------------------------------------------------------------------
__global__ __launch_bounds__(256) void kb2_fin(
    const float* __restrict__ part, const float* __restrict__ zpart,
    const float* __restrict__ qw, const float* __restrict__ qb,
    u16* __restrict__ M, float* __restrict__ T) {
  const int b = blockIdx.y;
  const int cs0 = blockIdx.x * 16;
  const int tid = threadIdx.x;
  __shared__ float cs[16][128];
  __shared__ float Zs[128];
  if (tid < 128) {
    float s = 0.f;
    for (int kc = 0; kc < NC; ++kc)
      s += zpart[((size_t)kc * B_ + b) * C_ + tid];
    Zs[tid] = s;
  }
  __syncthreads();
#pragma unroll
  for (int i = 0; i < 8; ++i) {
    const int e = tid + i * 256;
    const int cl = e >> 7, d = e & 127;
    float s = 0.f;
    for (int kc = 0; kc < NC; ++kc)
      s += part[(((size_t)kc * B_ + b) * C_ + (cs0 + cl)) * C_ + d];
    cs[cl][d] = s / Zs[d];
  }
  __syncthreads();
  const int cl = tid >> 4, e0 = (tid & 15) * 8;
  float m[8] = {};
  for (int d = 0; d < 128; ++d) {
    const float cv = cs[cl][d];
    const float* qr = qw + d * C_ + e0;
#pragma unroll
    for (int j = 0; j < 8; ++j) m[j] += cv * qr[j];
  }
  u16* mp = M + ((size_t)b * C_ + cs0 + cl) * C_ + e0;
#pragma unroll
  for (int j = 0; j < 8; ++j) mp[j] = (u16)f2bf(m[j]);
  if (tid < 16) {
    float tv = 0.f;
    for (int d = 0; d < 128; ++d) tv += cs[tid][d] * qb[d];
    T[b * C_ + cs0 + tid] = tv;
  }
}

// ---------------------------------------------------------------------------
// K4: out = M·q_feat + T (fp32).  grid (N/64, B), 256 thr = 4 waves.
// KA-style staging: q tile global->regs (coalesced, lane = n), cvtpk in
// regs, ds_write_b128 into transposed bf16 tile qt[n][d] (XOR-swizzled,
// 16 KB).  B-fragments = single conflict-free ds_read_b128.  MFMA
// D[c][n] (non-swapped) + round-8 proven 64-B-segment stores.
// Per-thread LDS ops: 4 writes + 16 reads (all b128), vs 128 ds_read_b32.
// ---------------------------------------------------------------------------
__global__ __launch_bounds__(256) void k4_out(const u16* __restrict__ M,
                                              const float* __restrict__ T,
                                              const float* __restrict__ q,
                                              float* __restrict__ out) {
  __shared__ u16 qt[SN4 * C_];  // [n][d] bf16 swizzled, 16 KB
  const int b = blockIdx.y;
  const int n0 = blockIdx.x * SN4;
  const int tid = threadIdx.x;
  const int w = tid >> 6, lane = tid & 63;
  const int lg = lane >> 4, li = lane & 15;

  // ---- stage: wave w loads d-rows [w*32, w*32+32), lane = n ----
  const float* qb = q + (size_t)b * C_ * N_ + n0;
  float xr[32];
#pragma unroll
  for (int j = 0; j < 32; ++j)
    xr[j] = qb[(size_t)(w * 32 + j) * N_ + lane];

  // M fragments (A operand, rows c) + T per output row (L2-hot)
  short8 mreg[2][4];
  const u16* Mb = M + (size_t)b * C_ * C_;
#pragma unroll
  for (int ct = 0; ct < 2; ++ct)
#pragma unroll
    for (int ks = 0; ks < 4; ++ks)
      mreg[ct][ks] = *reinterpret_cast<const short8*>(
          Mb + (w * 32 + ct * 16 + li) * C_ + ks * 32 + lg * 8);
  float tcv[2][4];
#pragma unroll
  for (int ct = 0; ct < 2; ++ct)
#pragma unroll
    for (int r = 0; r < 4; ++r)
      tcv[ct][r] = T[b * C_ + w * 32 + ct * 16 + lg * 4 + r];

  // ---- pack + transposed write: row n = lane, d-cols [w*32, +32) ----
#pragma unroll
  for (int o = 0; o < 4; ++o) {
    uint4 v;
    v.x = cvtpk(xr[o * 8 + 0], xr[o * 8 + 1]);
    v.y = cvtpk(xr[o * 8 + 2], xr[o * 8 + 3]);
    v.z = cvtpk(xr[o * 8 + 4], xr[o * 8 + 5]);
    v.w = cvtpk(xr[o * 8 + 6], xr[o * 8 + 7]);
    *reinterpret_cast<uint4*>(
        qt + lane * C_ + ((w * 32 + o * 8) ^ ((lane & 7) << 3))) = v;
  }
  __syncthreads();

  // ---- MFMA: D[c][n], A = M rows c, B = qt rows n ----
  f32x4 acc[2][4] = {};  // [ct][nt]; c = lg*4+r, n = nt*16+li
#pragma unroll
  for (int nt = 0; nt < 4; ++nt) {
    const int n = nt * 16 + li;
#pragma unroll
    for (int ks = 0; ks < 4; ++ks) {
      short8 bb = *reinterpret_cast<const short8*>(
          qt + n * C_ + ((ks * 32 + lg * 8) ^ ((n & 7) << 3)));
#pragma unroll
      for (int ct = 0; ct < 2; ++ct)
        acc[ct][nt] = __builtin_amdgcn_mfma_f32_16x16x32_bf16(
            mreg[ct][ks], bb, acc[ct][nt], 0, 0, 0);
    }
  }

  // ---- stores: per (ct,r): c-row; 16 lanes (li) write 64-B segments ----
#pragma unroll
  for (int ct = 0; ct < 2; ++ct)
#pragma unroll
    for (int r = 0; r < 4; ++r) {
      const int c = w * 32 + ct * 16 + lg * 4 + r;
      float* op = out + ((size_t)b * C_ + c) * N_ + n0;
      const float t = tcv[ct][r];
#pragma unroll
      for (int nt = 0; nt < 4; ++nt)
        op[nt * 16 + li] = acc[ct][nt][r] + t;
    }
}

// ---------------------------------------------------------------------------
extern "C" void kernel_launch(void* const* d_in, const int* in_sizes, int n_in,
                              void* d_out, int out_size, void* d_ws, size_t ws_size,
                              hipStream_t stream) {
  const float* q_feat  = (const float*)d_in[0];
  const float* kv_feat = (const float*)d_in[1];
  const float* q_w = (const float*)d_in[2];
  const float* q_b = (const float*)d_in[3];
  const float* k_w = (const float*)d_in[4];
  const float* k_b = (const float*)d_in[5];
  const float* v_w = (const float*)d_in[6];
  const float* v_b = (const float*)d_in[7];
  float* out = (float*)d_out;

  char* ws = (char*)d_ws;
  const size_t szPart = (size_t)NC * B_ * C_ * C_ * sizeof(float);  // 16 MB
  const size_t szZp   = (size_t)NC * B_ * C_ * sizeof(float);       // 128 KB
  const size_t szWbf  = (size_t)2 * C_ * C_ * sizeof(u16);          // 64 KB
  const size_t szM    = (size_t)B_ * C_ * C_ * sizeof(u16);         // 256 KB

  float* part  = (float*)ws;
  float* zpart = (float*)(ws + szPart);
  u16*   wbf   = (u16*)(ws + szPart + szZp);
  u16*   M     = (u16*)(ws + szPart + szZp + szWbf);
  float* T     = (float*)(ws + szPart + szZp + szWbf + szM);

  k0_wcvt<<<dim3(32), 256, 0, stream>>>(k_w, v_w, wbf);
  ka_projctx<<<dim3(NC, B_), 512, 0, stream>>>(kv_feat, wbf, k_b, v_b, part, zpart);
  kb2_fin<<<dim3(8, B_), 256, 0, stream>>>(part, zpart, q_w, q_b, M, T);
  k4_out<<<dim3(N_ / SN4, B_), 256, 0, stream>>>(M, T, q_feat, out);
}